// Round 16
// baseline (271.085 us; speedup 1.0000x reference)
//
#include <hip/hip_runtime.h>

// Fused CircularBoundaryBlock:
//   out = relu(LN(x + W2 @ relu(W1 @ [roll(x,1), x, roll(x,-1)] + b1) + b2))
// B=4, N=65536, H=128, fp32 I/O, bf16 MFMA internally.
//
// v17 = v16 (= v8, best: 98us/dispatch) + barrier-blocked LDS-read hoists.
//   __syncthreads() is a full fence: hipcc cannot hoist LDS reads above it,
//   even of buffers that are static after the prologue. Two such reads sit
//   on post-barrier critical paths every iteration:
//     1. W2 frags (8 b128 from w2s, constant): moved from post-B3 (under
//        the 8-wave port storm, ~120cyc before GEMM2 starts) to pre-B3,
//        where acc is dead (transient live ~= xreg 36 + wf 32 <= 128 arch).
//     2. gamma/beta quads (4 b128, constant): moved from post-B4 normalize
//        path to pre-B4.
//   Values survive the barrier in registers; only issue points move.
// Everything else byte-identical to v16: W1 frags in regs (AGPR), W2 frags
// in LDS, swapped-operand MFMA, T14 stage split + halo prefetch, LN-direct
// epilogue (ps2 partials + bpermute stats), direct f32x4 stores, 3
// barriers/iter, setprio, 256 thr, 512 blocks, 2 blocks/CU.
// Tripwire: FETCH/WRITE inflation = spill -> revert to v16, declare ceiling.

typedef __bf16 bf16x8 __attribute__((ext_vector_type(8)));
typedef __bf16 bf16x4 __attribute__((ext_vector_type(4)));
typedef float  f32x4  __attribute__((ext_vector_type(4)));

#define H      128
#define NB     65536        // rows per batch
#define TILE   64
#define XS     136          // x LDS stride (bf16 elems)
#define HSS    136          // h LDS stride (bf16 elems)
#define PSS    18           // ps2 stride (float2), 144 B: 16B-aligned rows
#define NTILES 4096         // 4 * 65536 / 64
#define GRID   512          // 2 blocks/CU * 256 CUs

__global__ __launch_bounds__(256, 2)
void cbb_kernel(const float* __restrict__ x, const float* __restrict__ W1,
                const float* __restrict__ b1, const float* __restrict__ W2,
                const float* __restrict__ b2, const float* __restrict__ gamma,
                const float* __restrict__ beta, float* __restrict__ out) {
    // xs (66*136 bf16) + hs (64*136 bf16) = 35360 B (no vs buffer)
    __shared__ __align__(16) char raw[(66 * XS + 64 * HSS) * 2];
    __bf16* xs = (__bf16*)raw;
    __bf16* hs = xs + 66 * XS;
    __shared__ __align__(16) __bf16 w2s[16384];    // W2 frags, 32 KB, persistent
    __shared__ __align__(16) float2 ps2[64 * PSS]; // LN partials, 9216 B
    __shared__ __align__(16) float s_b1[128], s_b2[128], s_gamma[128], s_beta[128];

    const int tid  = threadIdx.x;
    const int wid  = tid >> 6;
    const int lane = tid & 63;
    const int l    = lane & 15;   // MFMA n index (tile row, after swap)
    const int g    = lane >> 4;   // MFMA quad
    const int col0 = wid * 32;

    if (tid < 128) {
        s_b1[tid] = b1[tid];   s_b2[tid]   = b2[tid];
        s_gamma[tid] = gamma[tid]; s_beta[tid] = beta[tid];
    }

    // ---- W1 B-fragments persistent in registers (this wave's 32-col slice) ----
    bf16x8 w1f[12][2];
#pragma unroll
    for (int ks = 0; ks < 12; ++ks) {
#pragma unroll
        for (int ct = 0; ct < 2; ++ct) {
            const int cc = col0 + ct * 16 + l;
            bf16x8 f;
#pragma unroll
            for (int j = 0; j < 8; ++j)
                f[j] = (__bf16)W1[(ks * 32 + g * 8 + j) * H + cc];
            w1f[ks][ct] = f;
        }
    }

    // ---- W2 B-fragments -> LDS, fragment-ordered (once per block) ----
    // layout: w2s[w*4096 + ks*1024 + ct*512 + lane*8 + j]
    for (int idx = tid; idx < 16384; idx += 256) {
        const int j  = idx & 7;
        const int ln = (idx >> 3) & 63;
        const int ct = (idx >> 9) & 1;
        const int ks = (idx >> 10) & 3;
        const int w  = idx >> 12;
        const int row = ks * 32 + (ln >> 4) * 8 + j;
        const int col = w * 32 + ct * 16 + (ln & 15);
        w2s[idx] = (__bf16)W2[row * H + col];
    }
    const __bf16* w2w = w2s + wid * 4096;

    // ---- T14 prefetch: full 66-row halo tile (8 float4 + tid<64 halo) ----
    float4 xreg[8];
    float4 xhalo;
    {
        const int t  = blockIdx.x;
        const int b  = t >> 10;
        const int n0 = (t & 1023) << 6;
        const size_t rowbase = (size_t)b * NB;
#pragma unroll
        for (int s = 0; s < 8; ++s) {
            const int q = tid + s * 256;            // q < 2048 -> rows 0..63
            const int r = q >> 5, c = q & 31;
            const int grow = (n0 - 1 + r + NB) & (NB - 1);
            xreg[s] = *(const float4*)(x + ((rowbase + grow) * H + c * 4));
        }
        if (tid < 64) {                              // rows 64,65
            const int q = 2048 + tid;
            const int r = q >> 5, c = q & 31;
            const int grow = (n0 - 1 + r + NB) & (NB - 1);
            xhalo = *(const float4*)(x + ((rowbase + grow) * H + c * 4));
        }
    }

    for (int t = blockIdx.x; t < NTILES; t += GRID) {
        const int b  = t >> 10;
        const int n0 = (t & 1023) << 6;
        const size_t rowbase = (size_t)b * NB;

        // no loop-top barrier: prev-iter xs/hs readers are ordered by B4(ps2);
        // post-B4 work touches only ps2 + global.

        // ---- stage: consume prefetched regs -> xs (bf16) ----
#pragma unroll
        for (int s = 0; s < 8; ++s) {
            const int q = tid + s * 256;
            const int r = q >> 5, c = q & 31;
            bf16x4 v4;
            v4[0] = (__bf16)xreg[s].x; v4[1] = (__bf16)xreg[s].y;
            v4[2] = (__bf16)xreg[s].z; v4[3] = (__bf16)xreg[s].w;
            *(bf16x4*)(xs + r * XS + c * 4) = v4;
        }
        if (tid < 64) {
            const int q = 2048 + tid;
            const int r = q >> 5, c = q & 31;
            bf16x4 v4;
            v4[0] = (__bf16)xhalo.x; v4[1] = (__bf16)xhalo.y;
            v4[2] = (__bf16)xhalo.z; v4[3] = (__bf16)xhalo.w;
            *(bf16x4*)(xs + r * XS + c * 4) = v4;
        }
        __syncthreads();  // B2: xs tile visible

        // ---- issue next tile's loads; they fly under GEMM1/GEMM2/LN ----
        if (t + GRID < NTILES) {
            const int tn  = t + GRID;
            const int bn  = tn >> 10;
            const int n0n = (tn & 1023) << 6;
            const size_t rbn = (size_t)bn * NB;
#pragma unroll
            for (int s = 0; s < 8; ++s) {
                const int q = tid + s * 256;
                const int r = q >> 5, c = q & 31;
                const int grow = (n0n - 1 + r + NB) & (NB - 1);
                xreg[s] = *(const float4*)(x + ((rbn + grow) * H + c * 4));
            }
            if (tid < 64) {
                const int q = 2048 + tid;
                const int r = q >> 5, c = q & 31;
                const int grow = (n0n - 1 + r + NB) & (NB - 1);
                xhalo = *(const float4*)(x + ((rbn + grow) * H + c * 4));
            }
        }

        // ---- GEMM1 (swapped): acc[rt][ct] = D[hcol quad][tilerow] ----
        f32x4 acc[4][2];
#pragma unroll
        for (int rt = 0; rt < 4; ++rt)
#pragma unroll
            for (int ct = 0; ct < 2; ++ct)
                acc[rt][ct] = (f32x4){0.f, 0.f, 0.f, 0.f};

        __builtin_amdgcn_s_setprio(1);
#pragma unroll
        for (int ks = 0; ks < 12; ++ks) {
            const int k  = ks * 32 + g * 8;          // k in [0,384)
            const int ro = k >> 7, kc = k & 127;
#pragma unroll
            for (int rt = 0; rt < 4; ++rt) {
                const bf16x8 a = *(const bf16x8*)(xs + (rt * 16 + l + ro) * XS + kc);
                acc[rt][0] = __builtin_amdgcn_mfma_f32_16x16x32_bf16(w1f[ks][0], a, acc[rt][0], 0, 0, 0);
                acc[rt][1] = __builtin_amdgcn_mfma_f32_16x16x32_bf16(w1f[ks][1], a, acc[rt][1], 0, 0, 0);
            }
        }
        __builtin_amdgcn_s_setprio(0);

        // relu + bias -> hs: lane holds cols col0+ct*16+g*4..+3 of row rt*16+l
        {
            const f32x4 b1q0 = *(const f32x4*)(s_b1 + col0 + g * 4);
            const f32x4 b1q1 = *(const f32x4*)(s_b1 + col0 + 16 + g * 4);
#pragma unroll
            for (int rt = 0; rt < 4; ++rt) {
                bf16x4 h0, h1;
#pragma unroll
                for (int i = 0; i < 4; ++i) {
                    h0[i] = (__bf16)fmaxf(acc[rt][0][i] + b1q0[i], 0.f);
                    h1[i] = (__bf16)fmaxf(acc[rt][1][i] + b1q1[i], 0.f);
                }
                *(bf16x4*)(hs + (rt * 16 + l) * HSS + col0 + g * 4)      = h0;
                *(bf16x4*)(hs + (rt * 16 + l) * HSS + col0 + 16 + g * 4) = h1;
            }
        }

        // ---- HOIST 1: W2 frags (static after prologue) loaded PRE-B3 ----
        // acc is dead here; transient live = xreg + wf fits the arch budget.
        bf16x8 wf0[4], wf1[4];
#pragma unroll
        for (int ks = 0; ks < 4; ++ks) {
            wf0[ks] = *(const bf16x8*)(w2w + ks * 1024 + lane * 8);
            wf1[ks] = *(const bf16x8*)(w2w + ks * 1024 + 512 + lane * 8);
        }
        __syncthreads();  // B3: hs tile visible (wf already in regs)

        // ---- GEMM2 (swapped): delta[outcol quad][tilerow] ----
        f32x4 acc2[4][2];
#pragma unroll
        for (int rt = 0; rt < 4; ++rt)
#pragma unroll
            for (int ct = 0; ct < 2; ++ct)
                acc2[rt][ct] = (f32x4){0.f, 0.f, 0.f, 0.f};

        __builtin_amdgcn_s_setprio(1);
#pragma unroll
        for (int ks = 0; ks < 4; ++ks) {
#pragma unroll
            for (int rt = 0; rt < 4; ++rt) {
                const bf16x8 a = *(const bf16x8*)(hs + (rt * 16 + l) * HSS + ks * 32 + g * 8);
                acc2[rt][0] = __builtin_amdgcn_mfma_f32_16x16x32_bf16(wf0[ks], a, acc2[rt][0], 0, 0, 0);
                acc2[rt][1] = __builtin_amdgcn_mfma_f32_16x16x32_bf16(wf1[ks], a, acc2[rt][1], 0, 0, 0);
            }
        }
        __builtin_amdgcn_s_setprio(0);

        // ---- residual: v = x + delta + b2 (vectorized b64 x re-read) ----
        {
            const f32x4 b2q0 = *(const f32x4*)(s_b2 + col0 + g * 4);
            const f32x4 b2q1 = *(const f32x4*)(s_b2 + col0 + 16 + g * 4);
#pragma unroll
            for (int rt = 0; rt < 4; ++rt) {
                const bf16x4 xv0 = *(const bf16x4*)(xs + (rt * 16 + l + 1) * XS + col0 + g * 4);
                const bf16x4 xv1 = *(const bf16x4*)(xs + (rt * 16 + l + 1) * XS + col0 + 16 + g * 4);
#pragma unroll
                for (int i = 0; i < 4; ++i) {
                    acc2[rt][0][i] += b2q0[i] + (float)xv0[i];
                    acc2[rt][1][i] += b2q1[i] + (float)xv1[i];
                }
            }
        }

        // ---- LN partials: per-lane (s, sum v^2) over its 8 cols, per rt ----
#pragma unroll
        for (int rt = 0; rt < 4; ++rt) {
            float s = 0.f, qq = 0.f;
#pragma unroll
            for (int ct = 0; ct < 2; ++ct)
#pragma unroll
                for (int i = 0; i < 4; ++i) {
                    const float v = acc2[rt][ct][i];
                    s += v; qq += v * v;
                }
            ps2[(rt * 16 + l) * PSS + wid * 4 + g] = make_float2(s, qq);
        }

        // ---- HOIST 2: gamma/beta quads (static) loaded PRE-B4 ----
        const f32x4 gm0 = *(const f32x4*)(s_gamma + col0 + g * 4);
        const f32x4 gm1 = *(const f32x4*)(s_gamma + col0 + 16 + g * 4);
        const f32x4 bt0 = *(const f32x4*)(s_beta + col0 + g * 4);
        const f32x4 bt1 = *(const f32x4*)(s_beta + col0 + 16 + g * 4);
        __syncthreads();  // B4: partials visible; also frees xs/hs for next iter

        // ---- row stats for assigned row (= lane), chunked reads ----
        float mu, rv;
        {
            const f32x4* pp = (const f32x4*)(ps2 + lane * PSS);  // 144B rows
            float S = 0.f, Q = 0.f;
#pragma unroll
            for (int j = 0; j < 4; ++j) {
                const f32x4 e0 = pp[2 * j];
                const f32x4 e1 = pp[2 * j + 1];
                S += (e0[0] + e0[2]) + (e1[0] + e1[2]);
                Q += (e0[1] + e0[3]) + (e1[1] + e1[3]);
            }
            mu = S * (1.f / 128.f);
            const float var = Q * (1.f / 128.f) - mu * mu;
            rv = rsqrtf(var + 1e-5f);
        }

        // ---- normalize + relu in-reg, store f32x4 direct to global ----
        {
#pragma unroll
            for (int rt = 0; rt < 4; ++rt) {
                const float mur = __shfl(mu, (lane & 15) + rt * 16);
                const float rvr = __shfl(rv, (lane & 15) + rt * 16);
                float* op = out + (rowbase + n0 + rt * 16 + l) * H + col0;
                f32x4 o0, o1;
#pragma unroll
                for (int i = 0; i < 4; ++i) {
                    o0[i] = fmaxf((acc2[rt][0][i] - mur) * rvr * gm0[i] + bt0[i], 0.f);
                    o1[i] = fmaxf((acc2[rt][1][i] - mur) * rvr * gm1[i] + bt1[i], 0.f);
                }
                *(f32x4*)(op + g * 4)      = o0;
                *(f32x4*)(op + 16 + g * 4) = o1;
            }
        }
    }
}

extern "C" void kernel_launch(void* const* d_in, const int* in_sizes, int n_in,
                              void* d_out, int out_size, void* d_ws, size_t ws_size,
                              hipStream_t stream) {
    const float* x     = (const float*)d_in[0];
    const float* W1    = (const float*)d_in[1];
    const float* b1    = (const float*)d_in[2];
    const float* W2    = (const float*)d_in[3];
    const float* b2    = (const float*)d_in[4];
    const float* gamma = (const float*)d_in[5];
    const float* beta  = (const float*)d_in[6];
    float* out = (float*)d_out;

    // 512 blocks = 2 resident blocks/CU * 256 CUs; grid-stride over 4096 tiles
    cbb_kernel<<<GRID, 256, 0, stream>>>(x, W1, b1, W2, b2, gamma, beta, out);
}

// Round 17
// 261.678 us; speedup vs baseline: 1.0359x; 1.0359x over previous
//
#include <hip/hip_runtime.h>

// Fused CircularBoundaryBlock:
//   out = relu(LN(x + W2 @ relu(W1 @ [roll(x,1), x, roll(x,-1)] + b1) + b2))
// B=4, N=65536, H=128, fp32 I/O, bf16 MFMA internally.
//
// v18 = v16 = v8 restored (best measured: 98us/dispatch, 259.8us bench,
// reproduced twice). Final form after 17 measured rounds.
//
// Constraint ledger (all measured, see session journal):
//   - 8 waves/CU is an architectural invariant: live set (~120 regs) +
//     resident weights pin the 129-256-reg band; 6 escape attempts spilled
//     (v2/v4/v9/v10/v14) or added traffic (v10).
//   - x LDS staging is load-bearing: direct global A-frags = -170% (v15).
//   - Barrier vmcnt drain is NOT the stall (v12 neutral); LN pipelining
//     displaces GEMM1 issue (v11, -5%); constant-LDS-read hoisting spills
//     (v17: +64 transient regs -> scratch, -4%). v8's register slack is ~0.
// Structure: 64-row tiles, 4 waves column-split; W1 frags persistent in
// regs (AGPR side); W2 frags in LDS; swapped-operand MFMA (lane-contiguous
// epilogues); T14 async stage split + halo prefetch; LN-direct epilogue
// (ps2 partials + shfl stats redistribution, no vs buffer); direct f32x4
// global stores; biases/gamma/beta in tiny LDS; 3 barriers/iter; setprio
// around MFMA clusters. 256 thr, 512 blocks, 2 blocks/CU.

typedef __bf16 bf16x8 __attribute__((ext_vector_type(8)));
typedef __bf16 bf16x4 __attribute__((ext_vector_type(4)));
typedef float  f32x4  __attribute__((ext_vector_type(4)));

#define H      128
#define NB     65536        // rows per batch
#define TILE   64
#define XS     136          // x LDS stride (bf16 elems)
#define HSS    136          // h LDS stride (bf16 elems)
#define PSS    18           // ps2 stride (float2), 144 B: 16B-aligned rows
#define NTILES 4096         // 4 * 65536 / 64
#define GRID   512          // 2 blocks/CU * 256 CUs

__global__ __launch_bounds__(256, 2)
void cbb_kernel(const float* __restrict__ x, const float* __restrict__ W1,
                const float* __restrict__ b1, const float* __restrict__ W2,
                const float* __restrict__ b2, const float* __restrict__ gamma,
                const float* __restrict__ beta, float* __restrict__ out) {
    // xs (66*136 bf16) + hs (64*136 bf16) = 35360 B (no vs buffer)
    __shared__ __align__(16) char raw[(66 * XS + 64 * HSS) * 2];
    __bf16* xs = (__bf16*)raw;
    __bf16* hs = xs + 66 * XS;
    __shared__ __align__(16) __bf16 w2s[16384];    // W2 frags, 32 KB, persistent
    __shared__ __align__(16) float2 ps2[64 * PSS]; // LN partials, 9216 B
    __shared__ __align__(16) float s_b1[128], s_b2[128], s_gamma[128], s_beta[128];

    const int tid  = threadIdx.x;
    const int wid  = tid >> 6;
    const int lane = tid & 63;
    const int l    = lane & 15;   // MFMA n index (tile row, after swap)
    const int g    = lane >> 4;   // MFMA quad
    const int col0 = wid * 32;

    if (tid < 128) {
        s_b1[tid] = b1[tid];   s_b2[tid]   = b2[tid];
        s_gamma[tid] = gamma[tid]; s_beta[tid] = beta[tid];
    }

    // ---- W1 B-fragments persistent in registers (this wave's 32-col slice) ----
    bf16x8 w1f[12][2];
#pragma unroll
    for (int ks = 0; ks < 12; ++ks) {
#pragma unroll
        for (int ct = 0; ct < 2; ++ct) {
            const int cc = col0 + ct * 16 + l;
            bf16x8 f;
#pragma unroll
            for (int j = 0; j < 8; ++j)
                f[j] = (__bf16)W1[(ks * 32 + g * 8 + j) * H + cc];
            w1f[ks][ct] = f;
        }
    }

    // ---- W2 B-fragments -> LDS, fragment-ordered (once per block) ----
    // layout: w2s[w*4096 + ks*1024 + ct*512 + lane*8 + j]
    for (int idx = tid; idx < 16384; idx += 256) {
        const int j  = idx & 7;
        const int ln = (idx >> 3) & 63;
        const int ct = (idx >> 9) & 1;
        const int ks = (idx >> 10) & 3;
        const int w  = idx >> 12;
        const int row = ks * 32 + (ln >> 4) * 8 + j;
        const int col = w * 32 + ct * 16 + (ln & 15);
        w2s[idx] = (__bf16)W2[row * H + col];
    }
    const __bf16* w2w = w2s + wid * 4096;

    // ---- T14 prefetch: full 66-row halo tile (8 float4 + tid<64 halo) ----
    float4 xreg[8];
    float4 xhalo;
    {
        const int t  = blockIdx.x;
        const int b  = t >> 10;
        const int n0 = (t & 1023) << 6;
        const size_t rowbase = (size_t)b * NB;
#pragma unroll
        for (int s = 0; s < 8; ++s) {
            const int q = tid + s * 256;            // q < 2048 -> rows 0..63
            const int r = q >> 5, c = q & 31;
            const int grow = (n0 - 1 + r + NB) & (NB - 1);
            xreg[s] = *(const float4*)(x + ((rowbase + grow) * H + c * 4));
        }
        if (tid < 64) {                              // rows 64,65
            const int q = 2048 + tid;
            const int r = q >> 5, c = q & 31;
            const int grow = (n0 - 1 + r + NB) & (NB - 1);
            xhalo = *(const float4*)(x + ((rowbase + grow) * H + c * 4));
        }
    }

    for (int t = blockIdx.x; t < NTILES; t += GRID) {
        const int b  = t >> 10;
        const int n0 = (t & 1023) << 6;
        const size_t rowbase = (size_t)b * NB;

        // no loop-top barrier: prev-iter xs/hs readers are ordered by B4(ps2);
        // post-B4 work touches only ps2 + global.

        // ---- stage: consume prefetched regs -> xs (bf16) ----
#pragma unroll
        for (int s = 0; s < 8; ++s) {
            const int q = tid + s * 256;
            const int r = q >> 5, c = q & 31;
            bf16x4 v4;
            v4[0] = (__bf16)xreg[s].x; v4[1] = (__bf16)xreg[s].y;
            v4[2] = (__bf16)xreg[s].z; v4[3] = (__bf16)xreg[s].w;
            *(bf16x4*)(xs + r * XS + c * 4) = v4;
        }
        if (tid < 64) {
            const int q = 2048 + tid;
            const int r = q >> 5, c = q & 31;
            bf16x4 v4;
            v4[0] = (__bf16)xhalo.x; v4[1] = (__bf16)xhalo.y;
            v4[2] = (__bf16)xhalo.z; v4[3] = (__bf16)xhalo.w;
            *(bf16x4*)(xs + r * XS + c * 4) = v4;
        }
        __syncthreads();  // B2: xs tile visible

        // ---- issue next tile's loads; they fly under GEMM1/GEMM2/LN ----
        if (t + GRID < NTILES) {
            const int tn  = t + GRID;
            const int bn  = tn >> 10;
            const int n0n = (tn & 1023) << 6;
            const size_t rbn = (size_t)bn * NB;
#pragma unroll
            for (int s = 0; s < 8; ++s) {
                const int q = tid + s * 256;
                const int r = q >> 5, c = q & 31;
                const int grow = (n0n - 1 + r + NB) & (NB - 1);
                xreg[s] = *(const float4*)(x + ((rbn + grow) * H + c * 4));
            }
            if (tid < 64) {
                const int q = 2048 + tid;
                const int r = q >> 5, c = q & 31;
                const int grow = (n0n - 1 + r + NB) & (NB - 1);
                xhalo = *(const float4*)(x + ((rbn + grow) * H + c * 4));
            }
        }

        // ---- GEMM1 (swapped): acc[rt][ct] = D[hcol quad][tilerow] ----
        f32x4 acc[4][2];
#pragma unroll
        for (int rt = 0; rt < 4; ++rt)
#pragma unroll
            for (int ct = 0; ct < 2; ++ct)
                acc[rt][ct] = (f32x4){0.f, 0.f, 0.f, 0.f};

        __builtin_amdgcn_s_setprio(1);
#pragma unroll
        for (int ks = 0; ks < 12; ++ks) {
            const int k  = ks * 32 + g * 8;          // k in [0,384)
            const int ro = k >> 7, kc = k & 127;
#pragma unroll
            for (int rt = 0; rt < 4; ++rt) {
                const bf16x8 a = *(const bf16x8*)(xs + (rt * 16 + l + ro) * XS + kc);
                acc[rt][0] = __builtin_amdgcn_mfma_f32_16x16x32_bf16(w1f[ks][0], a, acc[rt][0], 0, 0, 0);
                acc[rt][1] = __builtin_amdgcn_mfma_f32_16x16x32_bf16(w1f[ks][1], a, acc[rt][1], 0, 0, 0);
            }
        }
        __builtin_amdgcn_s_setprio(0);

        // relu + bias -> hs: lane holds cols col0+ct*16+g*4..+3 of row rt*16+l
        {
            const f32x4 b1q0 = *(const f32x4*)(s_b1 + col0 + g * 4);
            const f32x4 b1q1 = *(const f32x4*)(s_b1 + col0 + 16 + g * 4);
#pragma unroll
            for (int rt = 0; rt < 4; ++rt) {
                bf16x4 h0, h1;
#pragma unroll
                for (int i = 0; i < 4; ++i) {
                    h0[i] = (__bf16)fmaxf(acc[rt][0][i] + b1q0[i], 0.f);
                    h1[i] = (__bf16)fmaxf(acc[rt][1][i] + b1q1[i], 0.f);
                }
                *(bf16x4*)(hs + (rt * 16 + l) * HSS + col0 + g * 4)      = h0;
                *(bf16x4*)(hs + (rt * 16 + l) * HSS + col0 + 16 + g * 4) = h1;
            }
        }
        __syncthreads();  // B3: hs tile visible

        // ---- GEMM2 (swapped): delta[outcol quad][tilerow] ----
        f32x4 acc2[4][2];
#pragma unroll
        for (int rt = 0; rt < 4; ++rt)
#pragma unroll
            for (int ct = 0; ct < 2; ++ct)
                acc2[rt][ct] = (f32x4){0.f, 0.f, 0.f, 0.f};

        __builtin_amdgcn_s_setprio(1);
#pragma unroll
        for (int ks = 0; ks < 4; ++ks) {
            const bf16x8 wf0 = *(const bf16x8*)(w2w + ks * 1024 + lane * 8);
            const bf16x8 wf1 = *(const bf16x8*)(w2w + ks * 1024 + 512 + lane * 8);
#pragma unroll
            for (int rt = 0; rt < 4; ++rt) {
                const bf16x8 a = *(const bf16x8*)(hs + (rt * 16 + l) * HSS + ks * 32 + g * 8);
                acc2[rt][0] = __builtin_amdgcn_mfma_f32_16x16x32_bf16(wf0, a, acc2[rt][0], 0, 0, 0);
                acc2[rt][1] = __builtin_amdgcn_mfma_f32_16x16x32_bf16(wf1, a, acc2[rt][1], 0, 0, 0);
            }
        }
        __builtin_amdgcn_s_setprio(0);

        // ---- residual: v = x + delta + b2 (vectorized b64 x re-read) ----
        {
            const f32x4 b2q0 = *(const f32x4*)(s_b2 + col0 + g * 4);
            const f32x4 b2q1 = *(const f32x4*)(s_b2 + col0 + 16 + g * 4);
#pragma unroll
            for (int rt = 0; rt < 4; ++rt) {
                const bf16x4 xv0 = *(const bf16x4*)(xs + (rt * 16 + l + 1) * XS + col0 + g * 4);
                const bf16x4 xv1 = *(const bf16x4*)(xs + (rt * 16 + l + 1) * XS + col0 + 16 + g * 4);
#pragma unroll
                for (int i = 0; i < 4; ++i) {
                    acc2[rt][0][i] += b2q0[i] + (float)xv0[i];
                    acc2[rt][1][i] += b2q1[i] + (float)xv1[i];
                }
            }
        }

        // ---- LN partials: per-lane (s, sum v^2) over its 8 cols, per rt ----
#pragma unroll
        for (int rt = 0; rt < 4; ++rt) {
            float s = 0.f, qq = 0.f;
#pragma unroll
            for (int ct = 0; ct < 2; ++ct)
#pragma unroll
                for (int i = 0; i < 4; ++i) {
                    const float v = acc2[rt][ct][i];
                    s += v; qq += v * v;
                }
            ps2[(rt * 16 + l) * PSS + wid * 4 + g] = make_float2(s, qq);
        }
        __syncthreads();  // B4: partials visible; also frees xs/hs for next iter

        // ---- row stats for assigned row (= lane), chunked reads ----
        float mu, rv;
        {
            const f32x4* pp = (const f32x4*)(ps2 + lane * PSS);  // 144B rows
            float S = 0.f, Q = 0.f;
#pragma unroll
            for (int j = 0; j < 4; ++j) {
                const f32x4 e0 = pp[2 * j];
                const f32x4 e1 = pp[2 * j + 1];
                S += (e0[0] + e0[2]) + (e1[0] + e1[2]);
                Q += (e0[1] + e0[3]) + (e1[1] + e1[3]);
            }
            mu = S * (1.f / 128.f);
            const float var = Q * (1.f / 128.f) - mu * mu;
            rv = rsqrtf(var + 1e-5f);
        }

        // ---- normalize + relu in-reg, store f32x4 direct to global ----
        {
            const f32x4 gm0 = *(const f32x4*)(s_gamma + col0 + g * 4);
            const f32x4 gm1 = *(const f32x4*)(s_gamma + col0 + 16 + g * 4);
            const f32x4 bt0 = *(const f32x4*)(s_beta + col0 + g * 4);
            const f32x4 bt1 = *(const f32x4*)(s_beta + col0 + 16 + g * 4);
#pragma unroll
            for (int rt = 0; rt < 4; ++rt) {
                const float mur = __shfl(mu, (lane & 15) + rt * 16);
                const float rvr = __shfl(rv, (lane & 15) + rt * 16);
                float* op = out + (rowbase + n0 + rt * 16 + l) * H + col0;
                f32x4 o0, o1;
#pragma unroll
                for (int i = 0; i < 4; ++i) {
                    o0[i] = fmaxf((acc2[rt][0][i] - mur) * rvr * gm0[i] + bt0[i], 0.f);
                    o1[i] = fmaxf((acc2[rt][1][i] - mur) * rvr * gm1[i] + bt1[i], 0.f);
                }
                *(f32x4*)(op + g * 4)      = o0;
                *(f32x4*)(op + 16 + g * 4) = o1;
            }
        }
    }
}

extern "C" void kernel_launch(void* const* d_in, const int* in_sizes, int n_in,
                              void* d_out, int out_size, void* d_ws, size_t ws_size,
                              hipStream_t stream) {
    const float* x     = (const float*)d_in[0];
    const float* W1    = (const float*)d_in[1];
    const float* b1    = (const float*)d_in[2];
    const float* W2    = (const float*)d_in[3];
    const float* b2    = (const float*)d_in[4];
    const float* gamma = (const float*)d_in[5];
    const float* beta  = (const float*)d_in[6];
    float* out = (float*)d_out;

    // 512 blocks = 2 resident blocks/CU * 256 CUs; grid-stride over 4096 tiles
    cbb_kernel<<<GRID, 256, 0, stream>>>(x, W1, b1, W2, b2, gamma, beta, out);
}